// Round 7
// baseline (981.295 us; speedup 1.0000x reference)
//
#include <hip/hip_runtime.h>
#include <math.h>

#define SLOPE 0.01f
#define BSH  11          // destination bucket = dest >> 11  (2048 dests/bucket)
#define BMAX 64          // max buckets (N <= 131072)

__device__ __forceinline__ float lrelu(float v) { return v >= 0.f ? v : SLOPE * v; }

// Launder a pointer through a VGPR so uniformity analysis can't prove it
// scalar -> forces global_load (vmcnt) instead of s_load (lgkmcnt). This
// decouples W traffic from the xs ds_read lgkmcnt stream (the R6 stall).
__device__ __forceinline__ const float* vptr(const float* p) {
    unsigned long long u = (unsigned long long)p;
    asm("" : "+v"(u));
    return (const float*)u;
}

// ---------------------------------------------------------------------------
// GRU step (h0=0) for both layers, regenerate GCN weights, fold Wout/bout,
// and transpose W2 -> W2t[hu][j] for contiguous stage-2 loads.
// ---------------------------------------------------------------------------
__global__ void prep_k(const float* __restrict__ m1, const float* __restrict__ Wih1,
                       const float* __restrict__ bih1, const float* __restrict__ bhh1,
                       const float* __restrict__ m2, const float* __restrict__ Wih2,
                       const float* __restrict__ bih2, const float* __restrict__ bhh2,
                       const float* __restrict__ wtW1, const float* __restrict__ wtb1,
                       const float* __restrict__ wtW2, const float* __restrict__ wtb2,
                       const float* __restrict__ Wout, const float* __restrict__ bout,
                       const float* __restrict__ W2,
                       float* __restrict__ Wn1, float* __restrict__ Wn2,
                       float* __restrict__ wsum, float* __restrict__ bsum,
                       float* __restrict__ W2t) {
    __shared__ float nm[32];   // new_mem1 [0..15], new_mem2 [16..31]
    int t = threadIdx.x;
    if (t < 32) {
        int L = t >> 4, j = t & 15;
        const float* m   = L ? m2   : m1;
        const float* Wih = L ? Wih2 : Wih1;
        const float* bih = L ? bih2 : bih1;
        const float* bhh = L ? bhh2 : bhh1;
        float gr = bih[j], gz = bih[16 + j], gn = bih[32 + j];
        for (int k = 0; k < 16; ++k) {
            float mk = m[k];
            gr += Wih[j * 16 + k] * mk;
            gz += Wih[(16 + j) * 16 + k] * mk;
            gn += Wih[(32 + j) * 16 + k] * mk;
        }
        float r = 1.f / (1.f + expf(-(gr + bhh[j])));
        float z = 1.f / (1.f + expf(-(gz + bhh[16 + j])));
        float n = tanhf(gn + r * bhh[32 + j]);
        nm[t] = (1.f - z) * n;          // + z*h, h==0
    }
    __syncthreads();
    float s1 = wtb1[t], s2 = wtb2[t];
    for (int k = 0; k < 16; ++k) {
        s1 += wtW1[t * 16 + k] * nm[k];
        s2 += wtW2[t * 16 + k] * nm[16 + k];
    }
    Wn1[t] = s1;
    Wn2[t] = s2;
#pragma unroll
    for (int j = 0; j < 16; ++j) W2t[t * 16 + j] = W2[j * 256 + t];
    if (t < 16) wsum[t] = Wout[t] + Wout[16 + t];
    if (t == 0) bsum[0] = bout[0] + bout[1];
}

// ---------------------------------------------------------------------------
// CSR build: zero -> histogram(+rank) -> 3-pass scan -> bucketed 2-pass fill
// ---------------------------------------------------------------------------
__global__ void zero_k(int* __restrict__ cnt, int N) {
    int i = blockIdx.x * 256 + threadIdx.x;
    if (i < N) cnt[i] = 0;
}

__global__ void hist_k(int* __restrict__ cnt, const int* __restrict__ col,
                       int* __restrict__ rank, int E) {
    int e = blockIdx.x * 256 + threadIdx.x;
    if (e < E) rank[e] = atomicAdd(cnt + col[e], 1);
}

__global__ void sred_k(const int* __restrict__ cnt, int* __restrict__ bred, int N) {
    __shared__ int s[4];
    int i = blockIdx.x * 256 + threadIdx.x;
    int v = (i < N) ? cnt[i] : 0;
#pragma unroll
    for (int m = 1; m < 64; m <<= 1) v += __shfl_xor(v, m);
    if ((threadIdx.x & 63) == 0) s[threadIdx.x >> 6] = v;
    __syncthreads();
    if (threadIdx.x == 0) bred[blockIdx.x] = s[0] + s[1] + s[2] + s[3];
}

__global__ __launch_bounds__(512) void sscan_k(const int* __restrict__ bred,
                                               int* __restrict__ bscan,
                                               int* __restrict__ off,
                                               int NB, int N, int E) {
    __shared__ int s[512];
    int t = threadIdx.x;
    int v = (t < NB) ? bred[t] : 0;
    s[t] = v;
    __syncthreads();
    for (int d = 1; d < 512; d <<= 1) {
        int u = (t >= d) ? s[t - d] : 0;
        __syncthreads();
        s[t] += u;
        __syncthreads();
    }
    if (t < NB) bscan[t] = s[t] - v;   // exclusive
    if (t == 0) off[N] = E;
}

__global__ void sfin_k(const int* __restrict__ cnt, const int* __restrict__ bscan,
                       int* __restrict__ off, float* __restrict__ dis,
                       int* __restrict__ bcur, int N) {
    __shared__ int s[256];
    int t = threadIdx.x;
    int i = blockIdx.x * 256 + t;
    int v = (i < N) ? cnt[i] : 0;
    s[t] = v;
    __syncthreads();
    for (int d = 1; d < 256; d <<= 1) {
        int u = (t >= d) ? s[t - d] : 0;
        __syncthreads();
        s[t] += u;
        __syncthreads();
    }
    int ex = s[t] - v + bscan[blockIdx.x];
    if (i < N) {
        off[i] = ex;
        dis[i] = rsqrtf((float)(v + 1));   // in-degree + self-loop
        if ((i & ((1 << BSH) - 1)) == 0) bcur[i >> BSH] = ex;  // bucket base
    }
}

__global__ void fill1_k(const int* __restrict__ row, const int* __restrict__ col,
                        const int* __restrict__ rank, const int* __restrict__ off,
                        int* __restrict__ bcur, int2* __restrict__ stage, int E) {
    __shared__ int lcnt[BMAX];
    __shared__ int lbase[BMAX];
    const int t = threadIdx.x;
    if (t < BMAX) lcnt[t] = 0;
    __syncthreads();
    const int base = blockIdx.x * 2048;
    int r[8], pos[8], pk[8];
#pragma unroll
    for (int i = 0; i < 8; ++i) {
        int e = base + i * 256 + t;
        if (e < E) {
            int d = col[e];
            int b = d >> BSH;
            int slot = atomicAdd(&lcnt[b], 1);
            r[i]   = row[e];
            pos[i] = off[d] + rank[e];
            pk[i]  = (b << 16) | slot;
        } else pk[i] = -1;
    }
    __syncthreads();
    if (t < BMAX) lbase[t] = atomicAdd(bcur + t, lcnt[t]);
    __syncthreads();
#pragma unroll
    for (int i = 0; i < 8; ++i) {
        if (pk[i] >= 0) {
            int b = pk[i] >> 16, slot = pk[i] & 0xFFFF;
            stage[lbase[b] + slot] = make_int2(r[i], pos[i]);
        }
    }
}

__global__ void fill2_k(const int2* __restrict__ stage, int* __restrict__ srcs, int E) {
    int i0 = (blockIdx.x * 256 + threadIdx.x) * 2;
    if (i0 + 1 < E) {
        int4 v = *(const int4*)(stage + i0);   // 16B load (stage 16B-aligned)
        srcs[v.y] = v.x;
        srcs[v.w] = v.z;
    } else if (i0 < E) {
        int2 v = stage[i0];
        srcs[v.y] = v.x;
    }
}

// ---------------------------------------------------------------------------
// Fused MLP v3: xl1S = dis * (leaky(leaky(x@W1^T+b1)@W2t+b2) @ Wn1^T)
// xs node-major stride 132 (odd float4 stride -> conflict-free ds_read_b128);
// W1/W2t loaded via laundered per-lane global_load (vmcnt, broadcast) so the
// k-loop has no s_load/lgkmcnt mixing. part/h2s overlay xs after a barrier.
// ---------------------------------------------------------------------------
__global__ __launch_bounds__(256, 4) void mlp_k(
        const float* __restrict__ x, const float* __restrict__ W1,
        const float* __restrict__ b1, const float* __restrict__ W2t,
        const float* __restrict__ b2, const float* __restrict__ Wn1,
        const float* __restrict__ dis, float* __restrict__ xl, int N) {
    __shared__ float buf[64 * 132];      // 33792 B; xs then part/h2s overlay
    float* part = buf;                   // [(q*64+n)*17+j]  (4352 floats)
    float* h2s  = buf + 4352;            // [n*17+j]         (1088 floats)
    const int t    = threadIdx.x;
    const int nl   = t & 63;
    const int q    = __builtin_amdgcn_readfirstlane(t >> 6);  // wave-uniform
    const int node = blockIdx.x * 64 + nl;

    // ---- stage x tile: node-major, each thread stages its quarter-row ----
    if (node < N) {
        const float4* xr = (const float4*)(x + (size_t)node * 128) + q * 8;
#pragma unroll
        for (int kk = 0; kk < 8; ++kk)
            *(float4*)&buf[nl * 132 + q * 32 + kk * 4] = xr[kk];
    } else {
#pragma unroll
        for (int kk = 0; kk < 8; ++kk)
            *(float4*)&buf[nl * 132 + q * 32 + kk * 4] = make_float4(0.f, 0.f, 0.f, 0.f);
    }
    __syncthreads();

    // ---- stage 1+2: this wave's 64 hu values, 8 at a time ----
    float acc2[16];
#pragma unroll
    for (int j = 0; j < 16; ++j) acc2[j] = 0.f;
    for (int hh = 0; hh < 64; hh += 8) {
        const int hu0 = q * 64 + hh;
        const float* wb = vptr(W1 + (size_t)hu0 * 128);
        float a[8];
#pragma unroll
        for (int r = 0; r < 8; ++r) a[r] = 0.f;
        for (int k4 = 0; k4 < 128; k4 += 4) {
            float4 xv = *(const float4*)&buf[nl * 132 + k4];
#pragma unroll
            for (int r = 0; r < 8; ++r) {
                float4 wv = *(const float4*)(wb + r * 128 + k4);
                a[r] = fmaf(xv.w, wv.w,
                        fmaf(xv.z, wv.z,
                         fmaf(xv.y, wv.y,
                          fmaf(xv.x, wv.x, a[r]))));
            }
        }
        const float* w2r = vptr(W2t + hu0 * 16);
#pragma unroll
        for (int r = 0; r < 8; ++r) {
            float h1 = lrelu(a[r] + b1[hu0 + r]);
            float4 wa = *(const float4*)(w2r + r * 16);
            float4 wbv = *(const float4*)(w2r + r * 16 + 4);
            float4 wc = *(const float4*)(w2r + r * 16 + 8);
            float4 wd = *(const float4*)(w2r + r * 16 + 12);
            acc2[0]  = fmaf(wa.x, h1, acc2[0]);
            acc2[1]  = fmaf(wa.y, h1, acc2[1]);
            acc2[2]  = fmaf(wa.z, h1, acc2[2]);
            acc2[3]  = fmaf(wa.w, h1, acc2[3]);
            acc2[4]  = fmaf(wbv.x, h1, acc2[4]);
            acc2[5]  = fmaf(wbv.y, h1, acc2[5]);
            acc2[6]  = fmaf(wbv.z, h1, acc2[6]);
            acc2[7]  = fmaf(wbv.w, h1, acc2[7]);
            acc2[8]  = fmaf(wc.x, h1, acc2[8]);
            acc2[9]  = fmaf(wc.y, h1, acc2[9]);
            acc2[10] = fmaf(wc.z, h1, acc2[10]);
            acc2[11] = fmaf(wc.w, h1, acc2[11]);
            acc2[12] = fmaf(wd.x, h1, acc2[12]);
            acc2[13] = fmaf(wd.y, h1, acc2[13]);
            acc2[14] = fmaf(wd.z, h1, acc2[14]);
            acc2[15] = fmaf(wd.w, h1, acc2[15]);
        }
    }
    __syncthreads();   // everyone done reading xs; safe to overlay part
#pragma unroll
    for (int j = 0; j < 16; ++j) part[(q * 64 + nl) * 17 + j] = acc2[j];
    __syncthreads();

    // ---- h2 = lrelu(sum over quarters + b2) -> h2s ----
    {
        const int j0 = q * 4;
#pragma unroll
        for (int jj = 0; jj < 4; ++jj) {
            int j = j0 + jj;
            float s = b2[j];
#pragma unroll
            for (int qq = 0; qq < 4; ++qq) s += part[(qq * 64 + nl) * 17 + j];
            h2s[nl * 17 + j] = lrelu(s);
        }
    }
    __syncthreads();

    // ---- stage 3: o = h2 @ Wn1^T, scaled by dis ----
    {
        const int c0 = q * 4;
        float o[4];
#pragma unroll
        for (int cc = 0; cc < 4; ++cc) {
            float s = 0.f;
#pragma unroll
            for (int j = 0; j < 16; ++j)
                s = fmaf(Wn1[(c0 + cc) * 16 + j], h2s[nl * 17 + j], s);
            o[cc] = s;
        }
        if (node < N) {
            float d = dis[node];
            float4* xo = (float4*)(xl + (size_t)node * 16 + c0);
            *xo = make_float4(d * o[0], d * o[1], d * o[2], d * o[3]);
        }
    }
}

// ---------------------------------------------------------------------------
// Gather layer 1 (wave per node, 4 edges x 16 channels in flight)
// ---------------------------------------------------------------------------
__global__ void gather1_k(const int* __restrict__ off, const int* __restrict__ srcs,
                          const float* __restrict__ dis, const float* __restrict__ xin,
                          const float* __restrict__ bias, const float* __restrict__ Wn2,
                          float* __restrict__ xout, int N) {
    __shared__ float w[256];             // transposed: w[j*16+c] = Wn2[c*16+j]
    {
        int j = threadIdx.x >> 4, c = threadIdx.x & 15;
        w[threadIdx.x] = Wn2[c * 16 + j];
    }
    __syncthreads();
    int t = blockIdx.x * 256 + threadIdx.x;
    int n = t >> 6;
    if (n >= N) return;
    int lane = t & 63, sub = lane >> 4, c = lane & 15;
    float acc = (sub == 0) ? xin[(size_t)n * 16 + c] : 0.f;   // self term
    int e1 = off[n + 1];
    for (int e = off[n] + sub; e < e1; e += 4)
        acc += xin[(size_t)srcs[e] * 16 + c];
    acc += __shfl_xor(acc, 16);
    acc += __shfl_xor(acc, 32);
    float d = dis[n];
    float h = lrelu(fmaf(d, acc, bias[c]));
    float o = 0.f;
#pragma unroll
    for (int j = 0; j < 16; ++j) o = fmaf(w[j * 16 + c], __shfl(h, j, 16), o);
    if (sub == 0) xout[(size_t)n * 16 + c] = d * o;
}

// ---------------------------------------------------------------------------
// Gather layer 2 + final projection
// ---------------------------------------------------------------------------
__global__ void gather2_k(const int* __restrict__ off, const int* __restrict__ srcs,
                          const float* __restrict__ dis, const float* __restrict__ xin,
                          const float* __restrict__ bias, const float* __restrict__ wsum,
                          const float* __restrict__ bsum, float* __restrict__ out, int N) {
    int t = blockIdx.x * 256 + threadIdx.x;
    int n = t >> 6;
    if (n >= N) return;
    int lane = t & 63, sub = lane >> 4, c = lane & 15;
    float acc = (sub == 0) ? xin[(size_t)n * 16 + c] : 0.f;
    int e1 = off[n + 1];
    for (int e = off[n] + sub; e < e1; e += 4)
        acc += xin[(size_t)srcs[e] * 16 + c];
    acc += __shfl_xor(acc, 16);
    acc += __shfl_xor(acc, 32);
    float v = wsum[c] * lrelu(fmaf(dis[n], acc, bias[c]));
#pragma unroll
    for (int m = 1; m < 16; m <<= 1) v += __shfl_xor(v, m);
    if (lane == 0) out[n] = v + bsum[0];
}

// ---------------------------------------------------------------------------
extern "C" void kernel_launch(void* const* d_in, const int* in_sizes, int n_in,
                              void* d_out, int out_size, void* d_ws, size_t ws_size,
                              hipStream_t stream) {
    const float* x      = (const float*)d_in[0];
    const int*   edge   = (const int*)d_in[1];
    const float* W1     = (const float*)d_in[2];
    const float* b1     = (const float*)d_in[3];
    const float* W2     = (const float*)d_in[4];
    const float* b2     = (const float*)d_in[5];
    const float* mem1   = (const float*)d_in[6];
    const float* g1_Wih = (const float*)d_in[7];
    const float* g1_bih = (const float*)d_in[9];
    const float* g1_bhh = (const float*)d_in[10];
    const float* wt1_W  = (const float*)d_in[11];
    const float* wt1_b  = (const float*)d_in[12];
    const float* gcn1_b = (const float*)d_in[13];
    const float* mem2   = (const float*)d_in[14];
    const float* g2_Wih = (const float*)d_in[15];
    const float* g2_bih = (const float*)d_in[17];
    const float* g2_bhh = (const float*)d_in[18];
    const float* wt2_W  = (const float*)d_in[19];
    const float* wt2_b  = (const float*)d_in[20];
    const float* gcn2_b = (const float*)d_in[21];
    const float* Wout   = (const float*)d_in[22];
    const float* bout   = (const float*)d_in[23];
    float* out = (float*)d_out;

    const int N = in_sizes[0] / 128;
    const int E = in_sizes[1] / 2;
    const int* row = edge;
    const int* col = edge + E;

    const int gN  = (N + 255) / 256;       // blocks over nodes
    const int gE  = (E + 255) / 256;       // blocks over edges
    const int gM  = (N + 63) / 64;         // mlp blocks (64 nodes each)
    const int gG  = (N * 64 + 255) / 256;  // gather blocks (wave per node)
    const int gF1 = (E + 2047) / 2048;     // fill1 blocks (2048 edges each)
    const int gF2 = (E + 511) / 512;       // fill2 blocks (512 entries each)
    const int NB  = gN;                    // scan block count (<=512)

    float* ws    = (float*)d_ws;
    float* bufA  = ws;                        // [N*16] xl1 (dis-scaled)
    float* bufB  = bufA + (size_t)N * 16;     // [N*16] xl2 (dis-scaled)
    float* dis   = bufB + (size_t)N * 16;     // [N]
    float* sm    = dis + N;                   // smalls
    float* Wn1   = sm;
    float* Wn2   = sm + 256;
    float* wsum  = sm + 512;
    float* bsum  = sm + 528;
    float* W2t   = sm + 544;                  // [256*16] transposed W2
    int*   cnt   = (int*)(sm + 544 + 4096);   // [N]
    int*   off   = cnt + N;                   // [N+1]
    int*   rank  = off + N + 1;               // [E]
    int*   bred  = rank + E;                  // [NB]
    int*   bscan = bred + NB;                 // [NB]
    int*   bcur  = bscan + NB;                // [BMAX]
    int*   srcs  = bcur + BMAX;               // [E]
    // stage: 16B-aligned int2[E]
    size_t stoff = (size_t)(srcs + E - (int*)d_ws);
    stoff = (stoff + 3) & ~(size_t)3;
    int2*  stage = (int2*)((int*)d_ws + stoff);

    prep_k<<<1, 256, 0, stream>>>(mem1, g1_Wih, g1_bih, g1_bhh,
                                  mem2, g2_Wih, g2_bih, g2_bhh,
                                  wt1_W, wt1_b, wt2_W, wt2_b,
                                  Wout, bout, W2, Wn1, Wn2, wsum, bsum, W2t);
    zero_k<<<gN, 256, 0, stream>>>(cnt, N);
    hist_k<<<gE, 256, 0, stream>>>(cnt, col, rank, E);
    sred_k<<<gN, 256, 0, stream>>>(cnt, bred, N);
    sscan_k<<<1, 512, 0, stream>>>(bred, bscan, off, NB, N, E);
    sfin_k<<<gN, 256, 0, stream>>>(cnt, bscan, off, dis, bcur, N);
    fill1_k<<<gF1, 256, 0, stream>>>(row, col, rank, off, bcur, stage, E);
    fill2_k<<<gF2, 256, 0, stream>>>(stage, srcs, E);
    mlp_k<<<gM, 256, 0, stream>>>(x, W1, b1, W2t, b2, Wn1, dis, bufA, N);
    gather1_k<<<gG, 256, 0, stream>>>(off, srcs, dis, bufA, gcn1_b, Wn2, bufB, N);
    gather2_k<<<gG, 256, 0, stream>>>(off, srcs, dis, bufB, gcn2_b, wsum, bsum, out, N);
}

// Round 8
// 625.539 us; speedup vs baseline: 1.5687x; 1.5687x over previous
//
#include <hip/hip_runtime.h>
#include <math.h>

#define SLOPE 0.01f
#define BSH  11          // destination bucket = dest >> 11  (2048 dests/bucket)
#define BMAX 64          // max buckets (N <= 131072)

typedef short  bf16x8 __attribute__((ext_vector_type(8)));
typedef float  f32x4  __attribute__((ext_vector_type(4)));

__device__ __forceinline__ float lrelu(float v) { return v >= 0.f ? v : SLOPE * v; }

__device__ __forceinline__ unsigned short f2bf(float v) {
    unsigned u = __float_as_uint(v);
    return (unsigned short)((u + 0x7FFFu + ((u >> 16) & 1u)) >> 16);   // RNE
}
__device__ __forceinline__ float bf2f(unsigned short b) {
    return __uint_as_float(((unsigned)b) << 16);
}

// ---------------------------------------------------------------------------
// GRU step (h0=0) for both layers, regenerate GCN weights, fold Wout/bout,
// and transpose W2 -> W2t[hu][j] for contiguous stage-2 scalar loads.
// ---------------------------------------------------------------------------
__global__ void prep_k(const float* __restrict__ m1, const float* __restrict__ Wih1,
                       const float* __restrict__ bih1, const float* __restrict__ bhh1,
                       const float* __restrict__ m2, const float* __restrict__ Wih2,
                       const float* __restrict__ bih2, const float* __restrict__ bhh2,
                       const float* __restrict__ wtW1, const float* __restrict__ wtb1,
                       const float* __restrict__ wtW2, const float* __restrict__ wtb2,
                       const float* __restrict__ Wout, const float* __restrict__ bout,
                       const float* __restrict__ W2,
                       float* __restrict__ Wn1, float* __restrict__ Wn2,
                       float* __restrict__ wsum, float* __restrict__ bsum,
                       float* __restrict__ W2t) {
    __shared__ float nm[32];   // new_mem1 [0..15], new_mem2 [16..31]
    int t = threadIdx.x;
    if (t < 32) {
        int L = t >> 4, j = t & 15;
        const float* m   = L ? m2   : m1;
        const float* Wih = L ? Wih2 : Wih1;
        const float* bih = L ? bih2 : bih1;
        const float* bhh = L ? bhh2 : bhh1;
        float gr = bih[j], gz = bih[16 + j], gn = bih[32 + j];
        for (int k = 0; k < 16; ++k) {
            float mk = m[k];
            gr += Wih[j * 16 + k] * mk;
            gz += Wih[(16 + j) * 16 + k] * mk;
            gn += Wih[(32 + j) * 16 + k] * mk;
        }
        float r = 1.f / (1.f + expf(-(gr + bhh[j])));
        float z = 1.f / (1.f + expf(-(gz + bhh[16 + j])));
        float n = tanhf(gn + r * bhh[32 + j]);
        nm[t] = (1.f - z) * n;          // + z*h, h==0
    }
    __syncthreads();
    float s1 = wtb1[t], s2 = wtb2[t];
    for (int k = 0; k < 16; ++k) {
        s1 += wtW1[t * 16 + k] * nm[k];
        s2 += wtW2[t * 16 + k] * nm[16 + k];
    }
    Wn1[t] = s1;
    Wn2[t] = s2;
#pragma unroll
    for (int j = 0; j < 16; ++j) W2t[t * 16 + j] = W2[j * 256 + t];
    if (t < 16) wsum[t] = Wout[t] + Wout[16 + t];
    if (t == 0) bsum[0] = bout[0] + bout[1];
}

// Split W1 into bf16 hi/lo pair (for split-bf16 MFMA GEMM). 32768 elems.
__global__ void wsplit_k(const float* __restrict__ W1,
                         unsigned short* __restrict__ W1h,
                         unsigned short* __restrict__ W1l) {
    int i = blockIdx.x * 256 + threadIdx.x;
    float v = W1[i];
    unsigned short h = f2bf(v);
    W1h[i] = h;
    W1l[i] = f2bf(v - bf2f(h));
}

// ---------------------------------------------------------------------------
// CSR build: zero -> histogram(+rank) -> 3-pass scan -> bucketed 2-pass fill
// ---------------------------------------------------------------------------
__global__ void zero_k(int* __restrict__ cnt, int N) {
    int i = blockIdx.x * 256 + threadIdx.x;
    if (i < N) cnt[i] = 0;
}

__global__ void hist_k(int* __restrict__ cnt, const int* __restrict__ col,
                       int* __restrict__ rank, int E) {
    int e = blockIdx.x * 256 + threadIdx.x;
    if (e < E) rank[e] = atomicAdd(cnt + col[e], 1);
}

__global__ void sred_k(const int* __restrict__ cnt, int* __restrict__ bred, int N) {
    __shared__ int s[4];
    int i = blockIdx.x * 256 + threadIdx.x;
    int v = (i < N) ? cnt[i] : 0;
#pragma unroll
    for (int m = 1; m < 64; m <<= 1) v += __shfl_xor(v, m);
    if ((threadIdx.x & 63) == 0) s[threadIdx.x >> 6] = v;
    __syncthreads();
    if (threadIdx.x == 0) bred[blockIdx.x] = s[0] + s[1] + s[2] + s[3];
}

__global__ __launch_bounds__(512) void sscan_k(const int* __restrict__ bred,
                                               int* __restrict__ bscan,
                                               int* __restrict__ off,
                                               int NB, int N, int E) {
    __shared__ int s[512];
    int t = threadIdx.x;
    int v = (t < NB) ? bred[t] : 0;
    s[t] = v;
    __syncthreads();
    for (int d = 1; d < 512; d <<= 1) {
        int u = (t >= d) ? s[t - d] : 0;
        __syncthreads();
        s[t] += u;
        __syncthreads();
    }
    if (t < NB) bscan[t] = s[t] - v;   // exclusive
    if (t == 0) off[N] = E;
}

__global__ void sfin_k(const int* __restrict__ cnt, const int* __restrict__ bscan,
                       int* __restrict__ off, float* __restrict__ dis,
                       int* __restrict__ bcur, int N) {
    __shared__ int s[256];
    int t = threadIdx.x;
    int i = blockIdx.x * 256 + t;
    int v = (i < N) ? cnt[i] : 0;
    s[t] = v;
    __syncthreads();
    for (int d = 1; d < 256; d <<= 1) {
        int u = (t >= d) ? s[t - d] : 0;
        __syncthreads();
        s[t] += u;
        __syncthreads();
    }
    int ex = s[t] - v + bscan[blockIdx.x];
    if (i < N) {
        off[i] = ex;
        dis[i] = rsqrtf((float)(v + 1));   // in-degree + self-loop
        if ((i & ((1 << BSH) - 1)) == 0) bcur[i >> BSH] = ex;  // bucket base
    }
}

__global__ void fill1_k(const int* __restrict__ row, const int* __restrict__ col,
                        const int* __restrict__ rank, const int* __restrict__ off,
                        int* __restrict__ bcur, int2* __restrict__ stage, int E) {
    __shared__ int lcnt[BMAX];
    __shared__ int lbase[BMAX];
    const int t = threadIdx.x;
    if (t < BMAX) lcnt[t] = 0;
    __syncthreads();
    const int base = blockIdx.x * 2048;
    int r[8], pos[8], pk[8];
#pragma unroll
    for (int i = 0; i < 8; ++i) {
        int e = base + i * 256 + t;
        if (e < E) {
            int d = col[e];
            int b = d >> BSH;
            int slot = atomicAdd(&lcnt[b], 1);
            r[i]   = row[e];
            pos[i] = off[d] + rank[e];
            pk[i]  = (b << 16) | slot;
        } else pk[i] = -1;
    }
    __syncthreads();
    if (t < BMAX) lbase[t] = atomicAdd(bcur + t, lcnt[t]);
    __syncthreads();
#pragma unroll
    for (int i = 0; i < 8; ++i) {
        if (pk[i] >= 0) {
            int b = pk[i] >> 16, slot = pk[i] & 0xFFFF;
            stage[lbase[b] + slot] = make_int2(r[i], pos[i]);
        }
    }
}

__global__ void fill2_k(const int2* __restrict__ stage, int* __restrict__ srcs, int E) {
    int i0 = (blockIdx.x * 256 + threadIdx.x) * 2;
    if (i0 + 1 < E) {
        int4 v = *(const int4*)(stage + i0);   // 16B load (stage 16B-aligned)
        srcs[v.y] = v.x;
        srcs[v.w] = v.z;
    } else if (i0 < E) {
        int2 v = stage[i0];
        srcs[v.y] = v.x;
    }
}

// ---------------------------------------------------------------------------
// Fused MLP v4 (split-bf16 MFMA):
//   GEMM1 (100k x 128 x 256) via mfma_f32_16x16x32_bf16, x and W1 each split
//   into bf16 hi+lo; products hi*hi + hi*lo + lo*hi (lo*lo ~2^-18, dropped).
//   Stage2 (K=256 -> 16) in VALU via fp32 h1 LDS roundtrip (stride 257,
//   conflict-free). Stage3 (16x16) as before.
// Verified fragment layouts (m89/m91): A[m=lane&15][k=quad*8+j],
// B[k=quad*8+j][n=lane&15], D[m=quad*4+reg][n=lane&15].
// LDS: x_hi/x_lo bf16 (stride 136 => 16B-aligned ds_read_b128) overlaid
// after GEMM1 by h1s fp32 [64][257]; h2s tail. Peak 70144 B -> 2 blocks/CU.
// ---------------------------------------------------------------------------
__global__ __launch_bounds__(256, 2) void mlp_k(
        const float* __restrict__ x,
        const unsigned short* __restrict__ W1h,
        const unsigned short* __restrict__ W1l,
        const float* __restrict__ b1, const float* __restrict__ W2t,
        const float* __restrict__ b2, const float* __restrict__ Wn1,
        const float* __restrict__ dis, float* __restrict__ xl, int N) {
    __shared__ float sbuf[17536];                    // 70144 B
    unsigned short* xh  = (unsigned short*)sbuf;     // [64][136] bf16 hi
    unsigned short* xlo = (unsigned short*)sbuf + 8704;  // [64][136] bf16 lo
    float* h1s = sbuf;                               // [64][257] fp32 (overlay)
    float* h2s = sbuf + 16448;                       // [64][17]

    const int t      = threadIdx.x;
    const int nl     = t & 63;
    const int q      = __builtin_amdgcn_readfirstlane(t >> 6);  // wave-uniform
    const int lane15 = t & 15;
    const int quad   = (t & 63) >> 4;
    const int node   = blockIdx.x * 64 + nl;

    // ---- stage x: load fp32 quarter-row, split to bf16 hi/lo in LDS ----
    {
        unsigned* xh32 = (unsigned*)xh;
        unsigned* xl32 = (unsigned*)xlo;
        int base = nl * 68 + q * 16;                 // uint index (row stride 68)
        if (node < N) {
            const float4* xr = (const float4*)(x + (size_t)node * 128) + q * 8;
#pragma unroll
            for (int kk = 0; kk < 8; ++kk) {
                float4 v = xr[kk];
                unsigned short hx = f2bf(v.x), hy = f2bf(v.y);
                unsigned short hz = f2bf(v.z), hw = f2bf(v.w);
                unsigned short lx = f2bf(v.x - bf2f(hx)), ly = f2bf(v.y - bf2f(hy));
                unsigned short lz = f2bf(v.z - bf2f(hz)), lw = f2bf(v.w - bf2f(hw));
                xh32[base + kk * 2]     = (unsigned)hx | ((unsigned)hy << 16);
                xh32[base + kk * 2 + 1] = (unsigned)hz | ((unsigned)hw << 16);
                xl32[base + kk * 2]     = (unsigned)lx | ((unsigned)ly << 16);
                xl32[base + kk * 2 + 1] = (unsigned)lz | ((unsigned)lw << 16);
            }
        } else {
#pragma unroll
            for (int kk = 0; kk < 8; ++kk) {
                xh32[base + kk * 2] = 0u; xh32[base + kk * 2 + 1] = 0u;
                xl32[base + kk * 2] = 0u; xl32[base + kk * 2 + 1] = 0u;
            }
        }
    }
    __syncthreads();

    // ---- GEMM1: wave q owns hu in [64q, 64q+64); 4 m-tiles x 4 n-tiles ----
    f32x4 acc[4][4];
#pragma unroll
    for (int mt = 0; mt < 4; ++mt)
#pragma unroll
        for (int nt = 0; nt < 4; ++nt)
            acc[mt][nt] = (f32x4){0.f, 0.f, 0.f, 0.f};

#pragma unroll 1
    for (int ks = 0; ks < 4; ++ks) {
        bf16x8 ah[4], al[4];
        const int koff = ks * 32 + quad * 8;
#pragma unroll
        for (int mt = 0; mt < 4; ++mt) {
            ah[mt] = *(const bf16x8*)(xh  + (16 * mt + lane15) * 136 + koff);
            al[mt] = *(const bf16x8*)(xlo + (16 * mt + lane15) * 136 + koff);
        }
#pragma unroll
        for (int nt = 0; nt < 4; ++nt) {
            size_t wo = (size_t)(q * 64 + nt * 16 + lane15) * 128 + koff;
            bf16x8 bh = *(const bf16x8*)(W1h + wo);
            bf16x8 bl = *(const bf16x8*)(W1l + wo);
#pragma unroll
            for (int mt = 0; mt < 4; ++mt) {
                acc[mt][nt] = __builtin_amdgcn_mfma_f32_16x16x32_bf16(ah[mt], bh, acc[mt][nt], 0, 0, 0);
                acc[mt][nt] = __builtin_amdgcn_mfma_f32_16x16x32_bf16(ah[mt], bl, acc[mt][nt], 0, 0, 0);
                acc[mt][nt] = __builtin_amdgcn_mfma_f32_16x16x32_bf16(al[mt], bh, acc[mt][nt], 0, 0, 0);
            }
        }
    }
    __syncthreads();   // x tile dead; safe to overlay h1s

    // ---- epilogue GEMM1: h1s[node_local][hu] = lrelu(acc + b1[hu]) ----
#pragma unroll
    for (int nt = 0; nt < 4; ++nt) {
        int hu = q * 64 + nt * 16 + lane15;
        float bb = b1[hu];
#pragma unroll
        for (int mt = 0; mt < 4; ++mt) {
            int rbase = (16 * mt + quad * 4) * 257 + hu;
#pragma unroll
            for (int r = 0; r < 4; ++r)
                h1s[rbase + r * 257] = lrelu(acc[mt][nt][r] + bb);
        }
    }
    __syncthreads();

    // ---- stage2: a2[j] = sum_hu h1s[nl][hu] * W2t[hu][j], j in wave quarter ----
    {
        float a2[4] = {0.f, 0.f, 0.f, 0.f};
        const float* h1r = h1s + nl * 257;
        for (int hu = 0; hu < 256; hu += 4) {
#pragma unroll
            for (int u = 0; u < 4; ++u) {
                float h = h1r[hu + u];
                const float* wr = W2t + (hu + u) * 16 + q * 4;   // uniform -> s_load
                a2[0] = fmaf(h, wr[0], a2[0]);
                a2[1] = fmaf(h, wr[1], a2[1]);
                a2[2] = fmaf(h, wr[2], a2[2]);
                a2[3] = fmaf(h, wr[3], a2[3]);
            }
        }
#pragma unroll
        for (int jj = 0; jj < 4; ++jj) {
            int j = q * 4 + jj;
            h2s[nl * 17 + j] = lrelu(a2[jj] + b2[j]);
        }
    }
    __syncthreads();

    // ---- stage3: o = h2 @ Wn1^T, scaled by dis ----
    {
        const int c0 = q * 4;
        float o[4];
#pragma unroll
        for (int cc = 0; cc < 4; ++cc) {
            float s = 0.f;
#pragma unroll
            for (int j = 0; j < 16; ++j)
                s = fmaf(Wn1[(c0 + cc) * 16 + j], h2s[nl * 17 + j], s);
            o[cc] = s;
        }
        if (node < N) {
            float d = dis[node];
            float4* xo = (float4*)(xl + (size_t)node * 16 + c0);
            *xo = make_float4(d * o[0], d * o[1], d * o[2], d * o[3]);
        }
    }
}

// ---------------------------------------------------------------------------
// Gather layer 1 (wave per node, 4 edges x 16 channels in flight)
// ---------------------------------------------------------------------------
__global__ void gather1_k(const int* __restrict__ off, const int* __restrict__ srcs,
                          const float* __restrict__ dis, const float* __restrict__ xin,
                          const float* __restrict__ bias, const float* __restrict__ Wn2,
                          float* __restrict__ xout, int N) {
    __shared__ float w[256];             // transposed: w[j*16+c] = Wn2[c*16+j]
    {
        int j = threadIdx.x >> 4, c = threadIdx.x & 15;
        w[threadIdx.x] = Wn2[c * 16 + j];
    }
    __syncthreads();
    int t = blockIdx.x * 256 + threadIdx.x;
    int n = t >> 6;
    if (n >= N) return;
    int lane = t & 63, sub = lane >> 4, c = lane & 15;
    float acc = (sub == 0) ? xin[(size_t)n * 16 + c] : 0.f;   // self term
    int e1 = off[n + 1];
    for (int e = off[n] + sub; e < e1; e += 4)
        acc += xin[(size_t)srcs[e] * 16 + c];
    acc += __shfl_xor(acc, 16);
    acc += __shfl_xor(acc, 32);
    float d = dis[n];
    float h = lrelu(fmaf(d, acc, bias[c]));
    float o = 0.f;
#pragma unroll
    for (int j = 0; j < 16; ++j) o = fmaf(w[j * 16 + c], __shfl(h, j, 16), o);
    if (sub == 0) xout[(size_t)n * 16 + c] = d * o;
}

// ---------------------------------------------------------------------------
// Gather layer 2 + final projection
// ---------------------------------------------------------------------------
__global__ void gather2_k(const int* __restrict__ off, const int* __restrict__ srcs,
                          const float* __restrict__ dis, const float* __restrict__ xin,
                          const float* __restrict__ bias, const float* __restrict__ wsum,
                          const float* __restrict__ bsum, float* __restrict__ out, int N) {
    int t = blockIdx.x * 256 + threadIdx.x;
    int n = t >> 6;
    if (n >= N) return;
    int lane = t & 63, sub = lane >> 4, c = lane & 15;
    float acc = (sub == 0) ? xin[(size_t)n * 16 + c] : 0.f;
    int e1 = off[n + 1];
    for (int e = off[n] + sub; e < e1; e += 4)
        acc += xin[(size_t)srcs[e] * 16 + c];
    acc += __shfl_xor(acc, 16);
    acc += __shfl_xor(acc, 32);
    float v = wsum[c] * lrelu(fmaf(dis[n], acc, bias[c]));
#pragma unroll
    for (int m = 1; m < 16; m <<= 1) v += __shfl_xor(v, m);
    if (lane == 0) out[n] = v + bsum[0];
}

// ---------------------------------------------------------------------------
extern "C" void kernel_launch(void* const* d_in, const int* in_sizes, int n_in,
                              void* d_out, int out_size, void* d_ws, size_t ws_size,
                              hipStream_t stream) {
    const float* x      = (const float*)d_in[0];
    const int*   edge   = (const int*)d_in[1];
    const float* W1     = (const float*)d_in[2];
    const float* b1     = (const float*)d_in[3];
    const float* W2     = (const float*)d_in[4];
    const float* b2     = (const float*)d_in[5];
    const float* mem1   = (const float*)d_in[6];
    const float* g1_Wih = (const float*)d_in[7];
    const float* g1_bih = (const float*)d_in[9];
    const float* g1_bhh = (const float*)d_in[10];
    const float* wt1_W  = (const float*)d_in[11];
    const float* wt1_b  = (const float*)d_in[12];
    const float* gcn1_b = (const float*)d_in[13];
    const float* mem2   = (const float*)d_in[14];
    const float* g2_Wih = (const float*)d_in[15];
    const float* g2_bih = (const float*)d_in[17];
    const float* g2_bhh = (const float*)d_in[18];
    const float* wt2_W  = (const float*)d_in[19];
    const float* wt2_b  = (const float*)d_in[20];
    const float* gcn2_b = (const float*)d_in[21];
    const float* Wout   = (const float*)d_in[22];
    const float* bout   = (const float*)d_in[23];
    float* out = (float*)d_out;

    const int N = in_sizes[0] / 128;
    const int E = in_sizes[1] / 2;
    const int* row = edge;
    const int* col = edge + E;

    const int gN  = (N + 255) / 256;       // blocks over nodes
    const int gE  = (E + 255) / 256;       // blocks over edges
    const int gM  = (N + 63) / 64;         // mlp blocks (64 nodes each)
    const int gG  = (N * 64 + 255) / 256;  // gather blocks (wave per node)
    const int gF1 = (E + 2047) / 2048;     // fill1 blocks (2048 edges each)
    const int gF2 = (E + 511) / 512;       // fill2 blocks (512 entries each)
    const int NB  = gN;                    // scan block count (<=512)

    float* ws    = (float*)d_ws;
    float* bufA  = ws;                        // [N*16] xl1 (dis-scaled)
    float* bufB  = bufA + (size_t)N * 16;     // [N*16] xl2 (dis-scaled)
    float* dis   = bufB + (size_t)N * 16;     // [N]
    float* sm    = dis + N;                   // smalls
    float* Wn1   = sm;
    float* Wn2   = sm + 256;
    float* wsum  = sm + 512;
    float* bsum  = sm + 528;
    float* W2t   = sm + 544;                  // [256*16] transposed W2
    unsigned short* W1h = (unsigned short*)(sm + 4640);   // [256*128] bf16 hi
    unsigned short* W1l = (unsigned short*)(sm + 21024);  // [256*128] bf16 lo
    int*   cnt   = (int*)(sm + 37408);        // [N]
    int*   off   = cnt + N;                   // [N+1]
    int*   rank  = off + N + 1;               // [E]
    int*   bred  = rank + E;                  // [NB]
    int*   bscan = bred + NB;                 // [NB]
    int*   bcur  = bscan + NB;                // [BMAX]
    int*   srcs  = bcur + BMAX;               // [E]
    // stage: 16B-aligned int2[E]
    size_t stoff = (size_t)(srcs + E - (int*)d_ws);
    stoff = (stoff + 3) & ~(size_t)3;
    int2*  stage = (int2*)((int*)d_ws + stoff);

    prep_k<<<1, 256, 0, stream>>>(mem1, g1_Wih, g1_bih, g1_bhh,
                                  mem2, g2_Wih, g2_bih, g2_bhh,
                                  wt1_W, wt1_b, wt2_W, wt2_b,
                                  Wout, bout, W2, Wn1, Wn2, wsum, bsum, W2t);
    wsplit_k<<<128, 256, 0, stream>>>(W1, W1h, W1l);
    zero_k<<<gN, 256, 0, stream>>>(cnt, N);
    hist_k<<<gE, 256, 0, stream>>>(cnt, col, rank, E);
    sred_k<<<gN, 256, 0, stream>>>(cnt, bred, N);
    sscan_k<<<1, 512, 0, stream>>>(bred, bscan, off, NB, N, E);
    sfin_k<<<gN, 256, 0, stream>>>(cnt, bscan, off, dis, bcur, N);
    fill1_k<<<gF1, 256, 0, stream>>>(row, col, rank, off, bcur, stage, E);
    fill2_k<<<gF2, 256, 0, stream>>>(stage, srcs, E);
    mlp_k<<<gM, 256, 0, stream>>>(x, W1h, W1l, b1, W2t, b2, Wn1, dis, bufA, N);
    gather1_k<<<gG, 256, 0, stream>>>(off, srcs, dis, bufA, gcn1_b, Wn2, bufB, N);
    gather2_k<<<gG, 256, 0, stream>>>(off, srcs, dis, bufB, gcn2_b, wsum, bsum, out, N);
}

// Round 9
// 540.090 us; speedup vs baseline: 1.8169x; 1.1582x over previous
//
#include <hip/hip_runtime.h>
#include <math.h>

#define SLOPE 0.01f
#define BKS   1024       // dests per bucket
#define BSH2  10         // log2(BKS)
#define NBKMAX 512

typedef short  bf16x8 __attribute__((ext_vector_type(8)));
typedef float  f32x4  __attribute__((ext_vector_type(4)));

__device__ __forceinline__ float lrelu(float v) { return v >= 0.f ? v : SLOPE * v; }

__device__ __forceinline__ unsigned short f2bf(float v) {
    unsigned u = __float_as_uint(v);
    return (unsigned short)((u + 0x7FFFu + ((u >> 16) & 1u)) >> 16);   // RNE
}
__device__ __forceinline__ float bf2f(unsigned short b) {
    return __uint_as_float(((unsigned)b) << 16);
}

// ---------------------------------------------------------------------------
// GRU step (h0=0) for both layers, regenerate GCN weights, fold Wout/bout,
// and transpose W2 -> W2t[hu][j] for contiguous stage-2 scalar loads.
// ---------------------------------------------------------------------------
__global__ void prep_k(const float* __restrict__ m1, const float* __restrict__ Wih1,
                       const float* __restrict__ bih1, const float* __restrict__ bhh1,
                       const float* __restrict__ m2, const float* __restrict__ Wih2,
                       const float* __restrict__ bih2, const float* __restrict__ bhh2,
                       const float* __restrict__ wtW1, const float* __restrict__ wtb1,
                       const float* __restrict__ wtW2, const float* __restrict__ wtb2,
                       const float* __restrict__ Wout, const float* __restrict__ bout,
                       const float* __restrict__ W2,
                       float* __restrict__ Wn1, float* __restrict__ Wn2,
                       float* __restrict__ wsum, float* __restrict__ bsum,
                       float* __restrict__ W2t) {
    __shared__ float nm[32];   // new_mem1 [0..15], new_mem2 [16..31]
    int t = threadIdx.x;
    if (t < 32) {
        int L = t >> 4, j = t & 15;
        const float* m   = L ? m2   : m1;
        const float* Wih = L ? Wih2 : Wih1;
        const float* bih = L ? bih2 : bih1;
        const float* bhh = L ? bhh2 : bhh1;
        float gr = bih[j], gz = bih[16 + j], gn = bih[32 + j];
        for (int k = 0; k < 16; ++k) {
            float mk = m[k];
            gr += Wih[j * 16 + k] * mk;
            gz += Wih[(16 + j) * 16 + k] * mk;
            gn += Wih[(32 + j) * 16 + k] * mk;
        }
        float r = 1.f / (1.f + expf(-(gr + bhh[j])));
        float z = 1.f / (1.f + expf(-(gz + bhh[16 + j])));
        float n = tanhf(gn + r * bhh[32 + j]);
        nm[t] = (1.f - z) * n;          // + z*h, h==0
    }
    __syncthreads();
    float s1 = wtb1[t], s2 = wtb2[t];
    for (int k = 0; k < 16; ++k) {
        s1 += wtW1[t * 16 + k] * nm[k];
        s2 += wtW2[t * 16 + k] * nm[16 + k];
    }
    Wn1[t] = s1;
    Wn2[t] = s2;
#pragma unroll
    for (int j = 0; j < 16; ++j) W2t[t * 16 + j] = W2[j * 256 + t];
    if (t < 16) wsum[t] = Wout[t] + Wout[16 + t];
    if (t == 0) bsum[0] = bout[0] + bout[1];
}

// Split W1 into bf16 hi/lo pair (for split-bf16 MFMA GEMM). 32768 elems.
__global__ void wsplit_k(const float* __restrict__ W1,
                         unsigned short* __restrict__ W1h,
                         unsigned short* __restrict__ W1l) {
    int i = blockIdx.x * 256 + threadIdx.x;
    float v = W1[i];
    unsigned short h = f2bf(v);
    W1h[i] = h;
    W1l[i] = f2bf(v - bf2f(h));
}

// ---------------------------------------------------------------------------
// CSR build v3 (no per-edge global atomics):
//   zb -> bucket count (LDS) -> bucket scan -> bucket scatter (dense chunks)
//   -> per-bucket process (LDS hist + scan + in-window scatter)
// ---------------------------------------------------------------------------
__global__ void zb_k(int* __restrict__ btot) {
    btot[blockIdx.x * 256 + threadIdx.x] = 0;
}

// count edges per coarse bucket (LDS privatized)
__global__ void bcnt_k(const int* __restrict__ col, int* __restrict__ btot,
                       int E, int NBK) {
    __shared__ int lc[NBKMAX];
    int t = threadIdx.x;
    for (int i = t; i < NBK; i += 256) lc[i] = 0;
    __syncthreads();
    int base = blockIdx.x * 4096;
#pragma unroll
    for (int i = 0; i < 16; ++i) {
        int e = base + i * 256 + t;
        if (e < E) atomicAdd(&lc[col[e] >> BSH2], 1);
    }
    __syncthreads();
    for (int i = t; i < NBK; i += 256)
        if (lc[i]) atomicAdd(btot + i, lc[i]);
}

// single-block exclusive scan of bucket totals -> bases + scatter cursors
__global__ __launch_bounds__(512) void bscan_k(const int* __restrict__ btot,
                                               int* __restrict__ bbase,
                                               int* __restrict__ bfill,
                                               int* __restrict__ off,
                                               int NBK, int N, int E) {
    __shared__ int s[512];
    int t = threadIdx.x;
    int v = (t < NBK) ? btot[t] : 0;
    s[t] = v;
    __syncthreads();
    for (int d = 1; d < 512; d <<= 1) {
        int u = (t >= d) ? s[t - d] : 0;
        __syncthreads();
        s[t] += u;
        __syncthreads();
    }
    int ex = s[t] - v;
    if (t < NBK) { bbase[t] = ex; bfill[t] = ex; }
    if (t == 0) { bbase[NBK] = E; off[N] = E; }
}

// scatter (src,dest) pairs into bucket-partitioned stage; per-(block,bucket)
// chunks are ~42 edges = 334 B -> dense writes (fill1-proven density).
__global__ void bscat_k(const int* __restrict__ row, const int* __restrict__ col,
                        int* __restrict__ bfill, int2* __restrict__ stage,
                        int E, int NBK) {
    __shared__ int lcnt[NBKMAX];
    __shared__ int lbase[NBKMAX];
    int t = threadIdx.x;
    for (int i = t; i < NBK; i += 256) lcnt[i] = 0;
    __syncthreads();
    int base = blockIdx.x * 4096;
    int r[16], d[16], sl[16];
#pragma unroll
    for (int i = 0; i < 16; ++i) {
        int e = base + i * 256 + t;
        if (e < E) {
            r[i]  = row[e];
            d[i]  = col[e];
            sl[i] = atomicAdd(&lcnt[d[i] >> BSH2], 1);
        } else d[i] = -1;
    }
    __syncthreads();
    for (int i = t; i < NBK; i += 256)
        lbase[i] = lcnt[i] ? atomicAdd(bfill + i, lcnt[i]) : 0;
    __syncthreads();
#pragma unroll
    for (int i = 0; i < 16; ++i) {
        if (d[i] >= 0)
            stage[lbase[d[i] >> BSH2] + sl[i]] = make_int2(r[i], d[i]);
    }
}

// one block per bucket: LDS histogram -> LDS scan -> off/dis -> in-window
// scatter of srcs (writes confined to ~130 KB, L2-resident). LDS atomics only.
__global__ void bproc_k(const int2* __restrict__ stage, const int* __restrict__ bbase,
                        int* __restrict__ off, float* __restrict__ dis,
                        int* __restrict__ srcs, int N) {
    __shared__ int lh[BKS];    // counts, then cursors
    __shared__ int lo[BKS];    // exclusive offsets
    __shared__ int ssc[256];   // scan temp
    const int b = blockIdx.x;
    const int t = threadIdx.x;
    const int e0 = bbase[b], e1 = bbase[b + 1];
#pragma unroll
    for (int i = 0; i < 4; ++i) lh[t * 4 + i] = 0;
    __syncthreads();
    for (int e = e0 + t; e < e1; e += 256) {
        int2 v = stage[e];
        atomicAdd(&lh[v.y & (BKS - 1)], 1);
    }
    __syncthreads();
    // exclusive scan of lh[0..BKS) : 4 elems per thread + 256-scan
    int c0 = lh[t * 4], c1 = lh[t * 4 + 1], c2 = lh[t * 4 + 2], c3 = lh[t * 4 + 3];
    int tot = c0 + c1 + c2 + c3;
    ssc[t] = tot;
    __syncthreads();
    for (int d = 1; d < 256; d <<= 1) {
        int u = (t >= d) ? ssc[t - d] : 0;
        __syncthreads();
        ssc[t] += u;
        __syncthreads();
    }
    int ex = ssc[t] - tot;
    lo[t * 4]     = ex;
    lo[t * 4 + 1] = ex + c0;
    lo[t * 4 + 2] = ex + c0 + c1;
    lo[t * 4 + 3] = ex + c0 + c1 + c2;
    // off / dis for this bucket's 4*t.. nodes
    {
        int cs[4] = {c0, c1, c2, c3};
#pragma unroll
        for (int i = 0; i < 4; ++i) {
            int node = b * BKS + t * 4 + i;
            if (node < N) {
                off[node] = e0 + lo[t * 4 + i];
                dis[node] = rsqrtf((float)(cs[i] + 1));   // in-degree + self-loop
            }
        }
    }
    __syncthreads();
#pragma unroll
    for (int i = 0; i < 4; ++i) lh[t * 4 + i] = lo[t * 4 + i];   // cursors
    __syncthreads();
    for (int e = e0 + t; e < e1; e += 256) {
        int2 w = stage[e];
        int pos = e0 + atomicAdd(&lh[w.y & (BKS - 1)], 1);
        srcs[pos] = w.x;
    }
}

// ---------------------------------------------------------------------------
// Fused MLP v4 (split-bf16 MFMA):
//   GEMM1 (100k x 128 x 256) via mfma_f32_16x16x32_bf16, x and W1 each split
//   into bf16 hi+lo; products hi*hi + hi*lo + lo*hi (lo*lo ~2^-18, dropped).
//   Stage2 (K=256 -> 16) in VALU via fp32 h1 LDS roundtrip (stride 257,
//   conflict-free). Stage3 (16x16) as before.
// ---------------------------------------------------------------------------
__global__ __launch_bounds__(256, 2) void mlp_k(
        const float* __restrict__ x,
        const unsigned short* __restrict__ W1h,
        const unsigned short* __restrict__ W1l,
        const float* __restrict__ b1, const float* __restrict__ W2t,
        const float* __restrict__ b2, const float* __restrict__ Wn1,
        const float* __restrict__ dis, float* __restrict__ xl, int N) {
    __shared__ float sbuf[17536];                    // 70144 B
    unsigned short* xh  = (unsigned short*)sbuf;     // [64][136] bf16 hi
    unsigned short* xlo = (unsigned short*)sbuf + 8704;  // [64][136] bf16 lo
    float* h1s = sbuf;                               // [64][257] fp32 (overlay)
    float* h2s = sbuf + 16448;                       // [64][17]

    const int t      = threadIdx.x;
    const int nl     = t & 63;
    const int q      = __builtin_amdgcn_readfirstlane(t >> 6);  // wave-uniform
    const int lane15 = t & 15;
    const int quad   = (t & 63) >> 4;
    const int node   = blockIdx.x * 64 + nl;

    // ---- stage x: load fp32 quarter-row, split to bf16 hi/lo in LDS ----
    {
        unsigned* xh32 = (unsigned*)xh;
        unsigned* xl32 = (unsigned*)xlo;
        int base = nl * 68 + q * 16;                 // uint index (row stride 68)
        if (node < N) {
            const float4* xr = (const float4*)(x + (size_t)node * 128) + q * 8;
#pragma unroll
            for (int kk = 0; kk < 8; ++kk) {
                float4 v = xr[kk];
                unsigned short hx = f2bf(v.x), hy = f2bf(v.y);
                unsigned short hz = f2bf(v.z), hw = f2bf(v.w);
                unsigned short lx = f2bf(v.x - bf2f(hx)), ly = f2bf(v.y - bf2f(hy));
                unsigned short lz = f2bf(v.z - bf2f(hz)), lw = f2bf(v.w - bf2f(hw));
                xh32[base + kk * 2]     = (unsigned)hx | ((unsigned)hy << 16);
                xh32[base + kk * 2 + 1] = (unsigned)hz | ((unsigned)hw << 16);
                xl32[base + kk * 2]     = (unsigned)lx | ((unsigned)ly << 16);
                xl32[base + kk * 2 + 1] = (unsigned)lz | ((unsigned)lw << 16);
            }
        } else {
#pragma unroll
            for (int kk = 0; kk < 8; ++kk) {
                xh32[base + kk * 2] = 0u; xh32[base + kk * 2 + 1] = 0u;
                xl32[base + kk * 2] = 0u; xl32[base + kk * 2 + 1] = 0u;
            }
        }
    }
    __syncthreads();

    // ---- GEMM1: wave q owns hu in [64q, 64q+64); 4 m-tiles x 4 n-tiles ----
    f32x4 acc[4][4];
#pragma unroll
    for (int mt = 0; mt < 4; ++mt)
#pragma unroll
        for (int nt = 0; nt < 4; ++nt)
            acc[mt][nt] = (f32x4){0.f, 0.f, 0.f, 0.f};

#pragma unroll 1
    for (int ks = 0; ks < 4; ++ks) {
        bf16x8 ah[4], al[4];
        const int koff = ks * 32 + quad * 8;
#pragma unroll
        for (int mt = 0; mt < 4; ++mt) {
            ah[mt] = *(const bf16x8*)(xh  + (16 * mt + lane15) * 136 + koff);
            al[mt] = *(const bf16x8*)(xlo + (16 * mt + lane15) * 136 + koff);
        }
#pragma unroll
        for (int nt = 0; nt < 4; ++nt) {
            size_t wo = (size_t)(q * 64 + nt * 16 + lane15) * 128 + koff;
            bf16x8 bh = *(const bf16x8*)(W1h + wo);
            bf16x8 bl = *(const bf16x8*)(W1l + wo);
#pragma unroll
            for (int mt = 0; mt < 4; ++mt) {
                acc[mt][nt] = __builtin_amdgcn_mfma_f32_16x16x32_bf16(ah[mt], bh, acc[mt][nt], 0, 0, 0);
                acc[mt][nt] = __builtin_amdgcn_mfma_f32_16x16x32_bf16(ah[mt], bl, acc[mt][nt], 0, 0, 0);
                acc[mt][nt] = __builtin_amdgcn_mfma_f32_16x16x32_bf16(al[mt], bh, acc[mt][nt], 0, 0, 0);
            }
        }
    }
    __syncthreads();   // x tile dead; safe to overlay h1s

    // ---- epilogue GEMM1: h1s[node_local][hu] = lrelu(acc + b1[hu]) ----
#pragma unroll
    for (int nt = 0; nt < 4; ++nt) {
        int hu = q * 64 + nt * 16 + lane15;
        float bb = b1[hu];
#pragma unroll
        for (int mt = 0; mt < 4; ++mt) {
            int rbase = (16 * mt + quad * 4) * 257 + hu;
#pragma unroll
            for (int r = 0; r < 4; ++r)
                h1s[rbase + r * 257] = lrelu(acc[mt][nt][r] + bb);
        }
    }
    __syncthreads();

    // ---- stage2: a2[j] = sum_hu h1s[nl][hu] * W2t[hu][j] ----
    {
        float a2[4] = {0.f, 0.f, 0.f, 0.f};
        const float* h1r = h1s + nl * 257;
        for (int hu = 0; hu < 256; hu += 4) {
#pragma unroll
            for (int u = 0; u < 4; ++u) {
                float h = h1r[hu + u];
                const float* wr = W2t + (hu + u) * 16 + q * 4;   // uniform -> s_load
                a2[0] = fmaf(h, wr[0], a2[0]);
                a2[1] = fmaf(h, wr[1], a2[1]);
                a2[2] = fmaf(h, wr[2], a2[2]);
                a2[3] = fmaf(h, wr[3], a2[3]);
            }
        }
#pragma unroll
        for (int jj = 0; jj < 4; ++jj) {
            int j = q * 4 + jj;
            h2s[nl * 17 + j] = lrelu(a2[jj] + b2[j]);
        }
    }
    __syncthreads();

    // ---- stage3: o = h2 @ Wn1^T, scaled by dis ----
    {
        const int c0 = q * 4;
        float o[4];
#pragma unroll
        for (int cc = 0; cc < 4; ++cc) {
            float s = 0.f;
#pragma unroll
            for (int j = 0; j < 16; ++j)
                s = fmaf(Wn1[(c0 + cc) * 16 + j], h2s[nl * 17 + j], s);
            o[cc] = s;
        }
        if (node < N) {
            float d = dis[node];
            float4* xo = (float4*)(xl + (size_t)node * 16 + c0);
            *xo = make_float4(d * o[0], d * o[1], d * o[2], d * o[3]);
        }
    }
}

// ---------------------------------------------------------------------------
// Gather layer 1 (wave per node, 4 edges x 16 channels in flight)
// ---------------------------------------------------------------------------
__global__ void gather1_k(const int* __restrict__ off, const int* __restrict__ srcs,
                          const float* __restrict__ dis, const float* __restrict__ xin,
                          const float* __restrict__ bias, const float* __restrict__ Wn2,
                          float* __restrict__ xout, int N) {
    __shared__ float w[256];             // transposed: w[j*16+c] = Wn2[c*16+j]
    {
        int j = threadIdx.x >> 4, c = threadIdx.x & 15;
        w[threadIdx.x] = Wn2[c * 16 + j];
    }
    __syncthreads();
    int t = blockIdx.x * 256 + threadIdx.x;
    int n = t >> 6;
    if (n >= N) return;
    int lane = t & 63, sub = lane >> 4, c = lane & 15;
    float acc = (sub == 0) ? xin[(size_t)n * 16 + c] : 0.f;   // self term
    int e1 = off[n + 1];
    for (int e = off[n] + sub; e < e1; e += 4)
        acc += xin[(size_t)srcs[e] * 16 + c];
    acc += __shfl_xor(acc, 16);
    acc += __shfl_xor(acc, 32);
    float d = dis[n];
    float h = lrelu(fmaf(d, acc, bias[c]));
    float o = 0.f;
#pragma unroll
    for (int j = 0; j < 16; ++j) o = fmaf(w[j * 16 + c], __shfl(h, j, 16), o);
    if (sub == 0) xout[(size_t)n * 16 + c] = d * o;
}

// ---------------------------------------------------------------------------
// Gather layer 2 + final projection
// ---------------------------------------------------------------------------
__global__ void gather2_k(const int* __restrict__ off, const int* __restrict__ srcs,
                          const float* __restrict__ dis, const float* __restrict__ xin,
                          const float* __restrict__ bias, const float* __restrict__ wsum,
                          const float* __restrict__ bsum, float* __restrict__ out, int N) {
    int t = blockIdx.x * 256 + threadIdx.x;
    int n = t >> 6;
    if (n >= N) return;
    int lane = t & 63, sub = lane >> 4, c = lane & 15;
    float acc = (sub == 0) ? xin[(size_t)n * 16 + c] : 0.f;
    int e1 = off[n + 1];
    for (int e = off[n] + sub; e < e1; e += 4)
        acc += xin[(size_t)srcs[e] * 16 + c];
    acc += __shfl_xor(acc, 16);
    acc += __shfl_xor(acc, 32);
    float v = wsum[c] * lrelu(fmaf(dis[n], acc, bias[c]));
#pragma unroll
    for (int m = 1; m < 16; m <<= 1) v += __shfl_xor(v, m);
    if (lane == 0) out[n] = v + bsum[0];
}

// ---------------------------------------------------------------------------
extern "C" void kernel_launch(void* const* d_in, const int* in_sizes, int n_in,
                              void* d_out, int out_size, void* d_ws, size_t ws_size,
                              hipStream_t stream) {
    const float* x      = (const float*)d_in[0];
    const int*   edge   = (const int*)d_in[1];
    const float* W1     = (const float*)d_in[2];
    const float* b1     = (const float*)d_in[3];
    const float* W2     = (const float*)d_in[4];
    const float* b2     = (const float*)d_in[5];
    const float* mem1   = (const float*)d_in[6];
    const float* g1_Wih = (const float*)d_in[7];
    const float* g1_bih = (const float*)d_in[9];
    const float* g1_bhh = (const float*)d_in[10];
    const float* wt1_W  = (const float*)d_in[11];
    const float* wt1_b  = (const float*)d_in[12];
    const float* gcn1_b = (const float*)d_in[13];
    const float* mem2   = (const float*)d_in[14];
    const float* g2_Wih = (const float*)d_in[15];
    const float* g2_bih = (const float*)d_in[17];
    const float* g2_bhh = (const float*)d_in[18];
    const float* wt2_W  = (const float*)d_in[19];
    const float* wt2_b  = (const float*)d_in[20];
    const float* gcn2_b = (const float*)d_in[21];
    const float* Wout   = (const float*)d_in[22];
    const float* bout   = (const float*)d_in[23];
    float* out = (float*)d_out;

    const int N = in_sizes[0] / 128;
    const int E = in_sizes[1] / 2;
    const int* row = edge;
    const int* col = edge + E;

    const int NBK = (N + BKS - 1) >> BSH2;   // coarse buckets (98 @ N=100k)
    const int gM  = (N + 63) / 64;           // mlp blocks (64 nodes each)
    const int gG  = (N * 64 + 255) / 256;    // gather blocks (wave per node)
    const int gB  = (E + 4095) / 4096;       // bcnt/bscat blocks

    float* ws    = (float*)d_ws;
    float* bufA  = ws;                        // [N*16] xl1 (dis-scaled)
    float* bufB  = bufA + (size_t)N * 16;     // [N*16] xl2 (dis-scaled)
    float* dis   = bufB + (size_t)N * 16;     // [N]
    float* sm    = dis + N;                   // smalls
    float* Wn1   = sm;
    float* Wn2   = sm + 256;
    float* wsum  = sm + 512;
    float* bsum  = sm + 528;
    float* W2t   = sm + 544;                  // [256*16] transposed W2
    unsigned short* W1h = (unsigned short*)(sm + 4640);   // [256*128] bf16 hi
    unsigned short* W1l = (unsigned short*)(sm + 21024);  // [256*128] bf16 lo
    int*   btot  = (int*)(sm + 37408);        // [512]
    int*   bbase = btot + 512;                // [513]
    int*   bfill = bbase + 513;               // [512]
    int*   off   = bfill + 512;               // [N+1]
    int*   srcs  = off + N + 1;               // [E]
    // stage: 16B-aligned int2[E]
    size_t stoff = (size_t)(srcs + E - (int*)d_ws);
    stoff = (stoff + 3) & ~(size_t)3;
    int2*  stage = (int2*)((int*)d_ws + stoff);

    prep_k<<<1, 256, 0, stream>>>(mem1, g1_Wih, g1_bih, g1_bhh,
                                  mem2, g2_Wih, g2_bih, g2_bhh,
                                  wt1_W, wt1_b, wt2_W, wt2_b,
                                  Wout, bout, W2, Wn1, Wn2, wsum, bsum, W2t);
    wsplit_k<<<128, 256, 0, stream>>>(W1, W1h, W1l);
    zb_k<<<2, 256, 0, stream>>>(btot);
    bcnt_k<<<gB, 256, 0, stream>>>(col, btot, E, NBK);
    bscan_k<<<1, 512, 0, stream>>>(btot, bbase, bfill, off, NBK, N, E);
    bscat_k<<<gB, 256, 0, stream>>>(row, col, bfill, stage, E, NBK);
    bproc_k<<<NBK, 256, 0, stream>>>(stage, bbase, off, dis, srcs, N);
    mlp_k<<<gM, 256, 0, stream>>>(x, W1h, W1l, b1, W2t, b2, Wn1, dis, bufA, N);
    gather1_k<<<gG, 256, 0, stream>>>(off, srcs, dis, bufA, gcn1_b, Wn2, bufB, N);
    gather2_k<<<gG, 256, 0, stream>>>(off, srcs, dis, bufB, gcn2_b, wsum, bsum, out, N);
}